// Round 3
// baseline (397.327 us; speedup 1.0000x reference)
//
#include <hip/hip_runtime.h>
#include <math.h>

namespace {
constexpr int kB = 256;
constexpr int kD = 128;
constexpr int kN = 500000;
constexpr int kKC = 2049;             // K + 1
constexpr int kNPair = kB * kKC;      // 524544
constexpr float kTInv = 1.0f / 0.07f;
constexpr float kMom = 0.5f;
constexpr int kRB = 256;              // reduction grid size
constexpr long long kM = (long long)kN * kD;    // 64,000,000 floats per bank
constexpr long long kTot = 2 * kM;
constexpr int kChunk = 2048;                    // elems per scan block
constexpr int kNB1 = (kN + kChunk - 1) / kChunk; // 245
}

// ---------- CSR setup: bucket pairs by row index ----------

__global__ __launch_bounds__(256) void zero2_kernel(int* __restrict__ A, int* __restrict__ cur)
{
    int i = blockIdx.x * 256 + threadIdx.x;
    if (i < kN) { A[i] = 0; cur[i] = 0; }
}

__global__ __launch_bounds__(256) void hist_kernel(const int* __restrict__ cidx, int* __restrict__ A)
{
    int i = blockIdx.x * 256 + threadIdx.x;
    if (i < kNPair) atomicAdd(&A[cidx[i]], 1);
}

__global__ __launch_bounds__(256) void scan1_kernel(const int* __restrict__ A, int* __restrict__ bsum)
{
    long long base = (long long)blockIdx.x * kChunk;
    int t = threadIdx.x;
    int s = 0;
    #pragma unroll
    for (int j = 0; j < 8; ++j) {
        long long i = base + t * 8 + j;
        if (i < kN) s += A[i];
    }
    __shared__ int lds[256];
    lds[t] = s; __syncthreads();
    for (int st = 128; st > 0; st >>= 1) {
        if (t < st) lds[t] += lds[t + st];
        __syncthreads();
    }
    if (t == 0) bsum[blockIdx.x] = lds[0];
}

__global__ __launch_bounds__(256) void scan2_kernel(
    const int* __restrict__ bsum, int* __restrict__ bpre, int* __restrict__ offs)
{
    int t = threadIdx.x;
    int v = (t < kNB1) ? bsum[t] : 0;
    __shared__ int lds[256];
    lds[t] = v; __syncthreads();
    for (int st = 1; st < 256; st <<= 1) {
        int add = (t >= st) ? lds[t - st] : 0;
        __syncthreads();
        lds[t] += add;
        __syncthreads();
    }
    if (t < kNB1) bpre[t] = lds[t] - v;       // exclusive
    if (t == kNB1 - 1) offs[kN] = lds[t];     // total = kNPair
}

__global__ __launch_bounds__(256) void scan3_kernel(
    const int* __restrict__ A, const int* __restrict__ bpre, int* __restrict__ offs)
{
    int t = threadIdx.x;
    long long base = (long long)blockIdx.x * kChunk;
    int c[8]; int s = 0;
    #pragma unroll
    for (int j = 0; j < 8; ++j) {
        long long i = base + t * 8 + j;
        c[j] = (i < kN) ? A[i] : 0;
        s += c[j];
    }
    __shared__ int lds[256];
    lds[t] = s; __syncthreads();
    for (int st = 1; st < 256; st <<= 1) {
        int add = (t >= st) ? lds[t - st] : 0;
        __syncthreads();
        lds[t] += add;
        __syncthreads();
    }
    int excl = lds[t] - s + bpre[blockIdx.x];
    #pragma unroll
    for (int j = 0; j < 8; ++j) {
        long long i = base + t * 8 + j;
        if (i < kN) { offs[i] = excl; excl += c[j]; }
    }
}

__global__ __launch_bounds__(256) void scatter_kernel(
    const int* __restrict__ cidx, const int* __restrict__ offs,
    int* __restrict__ cur, int* __restrict__ sorted)
{
    int p = blockIdx.x * 256 + threadIdx.x;
    if (p < kNPair) {
        int r = cidx[p];
        int pos = offs[r] + atomicAdd(&cur[r], 1);
        sorted[pos] = p;   // bucket order nondeterministic; e values are not
    }
}

// ---------- fused stream: copy both banks + compute all dots ----------
// One wave per row r: read mem1/mem2 row once (float2/lane), write the
// shifted output rows (scalar dword stores, coalesced; dest is off-by-one
// float so vector alignment is impossible), and for each (b,k) pair
// referencing row r compute both dots against cache-resident teacher/student.
__global__ __launch_bounds__(256) void fused_kernel(
    const float* __restrict__ mem1, const float* __restrict__ mem2,
    const float* __restrict__ teacher, const float* __restrict__ student,
    const int* __restrict__ offs, const int* __restrict__ sorted,
    float* __restrict__ out, float* __restrict__ e2, float* __restrict__ e1)
{
    int lane = threadIdx.x & 63;
    int wid  = (blockIdx.x * 256 + threadIdx.x) >> 6;
    int nw   = (gridDim.x * 256) >> 6;
    for (int r = wid; r < kN; r += nw) {
        long long rb = (long long)r * kD;
        float2 a = *reinterpret_cast<const float2*>(mem1 + rb + lane * 2);
        float2 b = *reinterpret_cast<const float2*>(mem2 + rb + lane * 2);
        float* o1 = out + 1 + rb;
        float* o2 = out + 1 + kM + rb;
        o1[lane * 2]     = a.x;
        o1[lane * 2 + 1] = a.y;
        o2[lane * 2]     = b.x;
        o2[lane * 2 + 1] = b.y;
        int off = offs[r];
        int cnt = offs[r + 1] - off;
        for (int i = 0; i < cnt; ++i) {
            int p  = sorted[off + i];
            int bb = p / kKC;
            const float2 tv = *reinterpret_cast<const float2*>(teacher + bb * kD + lane * 2);
            const float2 sv = *reinterpret_cast<const float2*>(student + bb * kD + lane * 2);
            float d1 = a.x * tv.x + a.y * tv.y;   // mem1 . teacher -> out_v2
            float d2 = b.x * sv.x + b.y * sv.y;   // mem2 . student -> out_v1
            #pragma unroll
            for (int o = 32; o > 0; o >>= 1) {
                d1 += __shfl_xor(d1, o);
                d2 += __shfl_xor(d2, o);
            }
            if (lane == 0) {
                e2[p] = __expf(d1 * kTInv);
                e1[p] = __expf(d2 * kTInv);
            }
        }
    }
}

// ---------- fallback path (R2): separate gather + copy ----------

__global__ __launch_bounds__(256) void dots_kernel(
    const float* __restrict__ mem1, const float* __restrict__ mem2,
    const float* __restrict__ teacher, const float* __restrict__ student,
    const int* __restrict__ cidx,
    float* __restrict__ e2, float* __restrict__ e1)
{
    int gtid = blockIdx.x * 256 + threadIdx.x;
    int wave = gtid >> 6;
    int lane = threadIdx.x & 63;
    if (wave >= kNPair) return;
    int b = wave / kKC;
    long long row = (long long)cidx[wave] * kD;
    const float2 m1 = *reinterpret_cast<const float2*>(mem1 + row + lane * 2);
    const float2 m2 = *reinterpret_cast<const float2*>(mem2 + row + lane * 2);
    const float2 tv = *reinterpret_cast<const float2*>(teacher + b * kD + lane * 2);
    const float2 sv = *reinterpret_cast<const float2*>(student + b * kD + lane * 2);
    float d1 = m1.x * tv.x + m1.y * tv.y;
    float d2 = m2.x * sv.x + m2.y * sv.y;
    #pragma unroll
    for (int off = 32; off > 0; off >>= 1) {
        d1 += __shfl_xor(d1, off);
        d2 += __shfl_xor(d2, off);
    }
    if (lane == 0) {
        e2[wave] = __expf(d1 * kTInv);
        e1[wave] = __expf(d2 * kTInv);
    }
}

__global__ __launch_bounds__(256) void copy_kernel(
    const float* __restrict__ mem1, const float* __restrict__ mem2,
    float* __restrict__ out)
{
    const long long NV4 = (kTot + 1) / 4;
    const long long KS  = kM / 4;
    const float4* m1v = reinterpret_cast<const float4*>(mem1);
    const float4* m2v = reinterpret_cast<const float4*>(mem2);
    float4* ov = reinterpret_cast<float4*>(out);
    long long stride = (long long)gridDim.x * 256;
    for (long long k = (long long)blockIdx.x * 256 + threadIdx.x; k < NV4; k += stride) {
        if (k == 0) {
            out[1] = mem1[0]; out[2] = mem1[1]; out[3] = mem1[2];
            out[kTot] = mem2[kM - 1];
            continue;
        }
        float4 r;
        if (k < KS) {
            float4 a = m1v[k - 1];
            float4 b = m1v[k];
            r = make_float4(a.w, b.x, b.y, b.z);
        } else if (k == KS) {
            r = make_float4(mem1[kM - 1], mem2[0], mem2[1], mem2[2]);
        } else {
            float4 a = m2v[k - KS - 1];
            float4 b = m2v[k - KS];
            r = make_float4(a.w, b.x, b.y, b.z);
        }
        ov[k] = r;
    }
}

// ---------- loss chain ----------

__global__ __launch_bounds__(256) void sums_kernel(
    const float* __restrict__ e2, const float* __restrict__ e1,
    float* __restrict__ p2, float* __restrict__ p1)
{
    __shared__ float s2[256], s1[256];
    float a2 = 0.f, a1 = 0.f;
    for (int i = blockIdx.x * 256 + threadIdx.x; i < kNPair; i += 256 * kRB) {
        a2 += e2[i];
        a1 += e1[i];
    }
    s2[threadIdx.x] = a2; s1[threadIdx.x] = a1;
    __syncthreads();
    for (int st = 128; st > 0; st >>= 1) {
        if ((int)threadIdx.x < st) {
            s2[threadIdx.x] += s2[threadIdx.x + st];
            s1[threadIdx.x] += s1[threadIdx.x + st];
        }
        __syncthreads();
    }
    if (threadIdx.x == 0) { p2[blockIdx.x] = s2[0]; p1[blockIdx.x] = s1[0]; }
}

__global__ __launch_bounds__(256) void z_kernel(
    const float* __restrict__ p2, const float* __restrict__ p1, float* __restrict__ z)
{
    __shared__ float s2[256], s1[256];
    s2[threadIdx.x] = p2[threadIdx.x];
    s1[threadIdx.x] = p1[threadIdx.x];
    __syncthreads();
    for (int st = 128; st > 0; st >>= 1) {
        if ((int)threadIdx.x < st) {
            s2[threadIdx.x] += s2[threadIdx.x + st];
            s1[threadIdx.x] += s1[threadIdx.x + st];
        }
        __syncthreads();
    }
    if (threadIdx.x == 0) {
        const float scale = (float)kN / (float)kNPair;
        z[0] = s2[0] * scale;
        z[1] = s1[0] * scale;
    }
}

__global__ __launch_bounds__(256) void lossp_kernel(
    const float* __restrict__ e2, const float* __restrict__ e1,
    const float* __restrict__ z, float* __restrict__ lp)
{
    const float mpn = 2048.0f / 500000.0f;
    const float noise = mpn + 1e-7f;
    const float iz2 = 1.0f / z[0];
    const float iz1 = 1.0f / z[1];
    float acc = 0.f;
    for (int i = blockIdx.x * 256 + threadIdx.x; i < kNPair; i += 256 * kRB) {
        int k = i % kKC;
        float x2 = e2[i] * iz2;
        float x1 = e1[i] * iz1;
        if (k == 0) {
            acc += __logf(x2 / (x2 + noise)) + __logf(x1 / (x1 + noise));
        } else {
            acc += __logf(mpn / (x2 + noise)) + __logf(mpn / (x1 + noise));
        }
    }
    __shared__ float s[256];
    s[threadIdx.x] = acc;
    __syncthreads();
    for (int st = 128; st > 0; st >>= 1) {
        if ((int)threadIdx.x < st) s[threadIdx.x] += s[threadIdx.x + st];
        __syncthreads();
    }
    if (threadIdx.x == 0) lp[blockIdx.x] = s[0];
}

__global__ __launch_bounds__(256) void final_kernel(
    const float* __restrict__ lp, float* __restrict__ out)
{
    __shared__ float s[256];
    s[threadIdx.x] = lp[threadIdx.x];
    __syncthreads();
    for (int st = 128; st > 0; st >>= 1) {
        if ((int)threadIdx.x < st) s[threadIdx.x] += s[threadIdx.x + st];
        __syncthreads();
    }
    if (threadIdx.x == 0) out[0] = -s[0] / (float)kB;
}

// ---------- momentum update of the 256 pos rows ----------

__global__ __launch_bounds__(64) void update_kernel(
    const float* __restrict__ mem1, const float* __restrict__ mem2,
    const float* __restrict__ student, const float* __restrict__ teacher,
    const int* __restrict__ pos_idx,
    float* __restrict__ out1, float* __restrict__ out2)
{
    int b = blockIdx.x;
    int lane = threadIdx.x;
    int p = pos_idx[b];
    for (int b2 = b + 1; b2 < kB; ++b2)
        if (pos_idx[b2] == p) return;   // a later write wins
    long long row = (long long)p * kD;
    float2 m1 = *reinterpret_cast<const float2*>(mem1 + row + lane * 2);
    float2 m2 = *reinterpret_cast<const float2*>(mem2 + row + lane * 2);
    float2 sv = *reinterpret_cast<const float2*>(student + b * kD + lane * 2);
    float2 tv = *reinterpret_cast<const float2*>(teacher + b * kD + lane * 2);
    float2 l1 = make_float2(m1.x * kMom + sv.x * (1.f - kMom),
                            m1.y * kMom + sv.y * (1.f - kMom));
    float2 l2 = make_float2(m2.x * kMom + tv.x * (1.f - kMom),
                            m2.y * kMom + tv.y * (1.f - kMom));
    float n1 = l1.x * l1.x + l1.y * l1.y;
    float n2 = l2.x * l2.x + l2.y * l2.y;
    #pragma unroll
    for (int off = 32; off > 0; off >>= 1) {
        n1 += __shfl_xor(n1, off);
        n2 += __shfl_xor(n2, off);
    }
    float i1 = 1.0f / sqrtf(n1);
    float i2 = 1.0f / sqrtf(n2);
    out1[row + lane * 2]     = l1.x * i1;
    out1[row + lane * 2 + 1] = l1.y * i1;
    out2[row + lane * 2]     = l2.x * i2;
    out2[row + lane * 2 + 1] = l2.y * i2;
}

extern "C" void kernel_launch(void* const* d_in, const int* in_sizes, int n_in,
                              void* d_out, int out_size, void* d_ws, size_t ws_size,
                              hipStream_t stream) {
    const float* student = (const float*)d_in[0];
    const float* teacher = (const float*)d_in[1];
    const float* mem1    = (const float*)d_in[2];
    const float* mem2    = (const float*)d_in[3];
    const int*   pos_idx = (const int*)d_in[4];
    const int*   cidx    = (const int*)d_in[5];

    float* out  = (float*)d_out;
    float* out1 = out + 1;
    float* out2 = out + 1 + kM;

    // ws layout
    float* ws = (float*)d_ws;
    float* e2 = ws;                         // kNPair
    float* e1 = e2 + kNPair;                // kNPair
    float* p2 = e1 + kNPair;                // kRB
    float* p1 = p2 + kRB;                   // kRB
    float* zz = p1 + kRB;                   // 2
    float* lp = zz + 2;                     // kRB
    int*   A      = (int*)(lp + kRB);       // kN   (counts, then cursor)
    int*   cur    = A + kN;                 // kN
    int*   offs   = cur + kN;               // kN + 1
    int*   bsum   = offs + kN + 1;          // kNB1
    int*   bpre   = bsum + kNB1;            // kNB1
    int*   sorted = bpre + kNB1;            // kNPair
    size_t need = (size_t)((char*)(sorted + kNPair) - (char*)d_ws);

    // ---- loss chain helpers are common to both paths ----
    if (ws_size >= need) {
        // CSR setup
        zero2_kernel<<<(kN + 255) / 256, 256, 0, stream>>>(A, cur);
        hist_kernel<<<(kNPair + 255) / 256, 256, 0, stream>>>(cidx, A);
        scan1_kernel<<<kNB1, 256, 0, stream>>>(A, bsum);
        scan2_kernel<<<1, 256, 0, stream>>>(bsum, bpre, offs);
        scan3_kernel<<<kNB1, 256, 0, stream>>>(A, bpre, offs);
        scatter_kernel<<<(kNPair + 255) / 256, 256, 0, stream>>>(cidx, offs, cur, sorted);
        // fused copy + dots
        fused_kernel<<<2048, 256, 0, stream>>>(mem1, mem2, teacher, student,
                                               offs, sorted, out, e2, e1);
    } else {
        // fallback: R2 path
        int nblocks = (kNPair + 3) / 4;
        dots_kernel<<<nblocks, 256, 0, stream>>>(mem1, mem2, teacher, student, cidx, e2, e1);
        copy_kernel<<<2048, 256, 0, stream>>>(mem1, mem2, out);
    }

    sums_kernel<<<kRB, 256, 0, stream>>>(e2, e1, p2, p1);
    z_kernel<<<1, 256, 0, stream>>>(p2, p1, zz);
    lossp_kernel<<<kRB, 256, 0, stream>>>(e2, e1, zz, lp);
    final_kernel<<<1, 256, 0, stream>>>(lp, out);
    update_kernel<<<kB, 64, 0, stream>>>(mem1, mem2, student, teacher, pos_idx, out1, out2);
}

// Round 4
// 372.892 us; speedup vs baseline: 1.0655x; 1.0655x over previous
//
#include <hip/hip_runtime.h>
#include <math.h>

namespace {
constexpr int kB = 256;
constexpr int kD = 128;
constexpr int kN = 500000;
constexpr int kKC = 2049;             // K + 1
constexpr int kNPair = kB * kKC;      // 524544
constexpr float kTInv = 1.0f / 0.07f;
constexpr float kMom = 0.5f;
constexpr int kRB = 256;              // reduction grid size
constexpr long long kM = (long long)kN * kD;    // 64,000,000 floats per bank
constexpr long long kTot = 2 * kM;
constexpr int kChunk = 2048;                    // elems per scan block
constexpr int kNB1 = (kN + kChunk - 1) / kChunk; // 245
constexpr long long kWL = 500000;     // total wave-loads (64 float4 each)
constexpr long long kWLB = 250000;    // wave-loads in bank 1
constexpr int kIters = 62;            // wave-loads per wave (8192 waves)
}

// ---------- CSR setup: bucket pairs by row index ----------

__global__ __launch_bounds__(256) void zero2_kernel(int* __restrict__ A, int* __restrict__ cur)
{
    int i = blockIdx.x * 256 + threadIdx.x;
    if (i < kN) { A[i] = 0; cur[i] = 0; }
}

__global__ __launch_bounds__(256) void hist_kernel(const int* __restrict__ cidx, int* __restrict__ A)
{
    int i = blockIdx.x * 256 + threadIdx.x;
    if (i < kNPair) atomicAdd(&A[cidx[i]], 1);
}

__global__ __launch_bounds__(256) void scan1_kernel(const int* __restrict__ A, int* __restrict__ bsum)
{
    long long base = (long long)blockIdx.x * kChunk;
    int t = threadIdx.x;
    int s = 0;
    #pragma unroll
    for (int j = 0; j < 8; ++j) {
        long long i = base + t * 8 + j;
        if (i < kN) s += A[i];
    }
    __shared__ int lds[256];
    lds[t] = s; __syncthreads();
    for (int st = 128; st > 0; st >>= 1) {
        if (t < st) lds[t] += lds[t + st];
        __syncthreads();
    }
    if (t == 0) bsum[blockIdx.x] = lds[0];
}

__global__ __launch_bounds__(256) void scan2_kernel(
    const int* __restrict__ bsum, int* __restrict__ bpre, int* __restrict__ offs)
{
    int t = threadIdx.x;
    int v = (t < kNB1) ? bsum[t] : 0;
    __shared__ int lds[256];
    lds[t] = v; __syncthreads();
    for (int st = 1; st < 256; st <<= 1) {
        int add = (t >= st) ? lds[t - st] : 0;
        __syncthreads();
        lds[t] += add;
        __syncthreads();
    }
    if (t < kNB1) bpre[t] = lds[t] - v;       // exclusive
    if (t == kNB1 - 1) offs[kN] = lds[t];     // total = kNPair
}

__global__ __launch_bounds__(256) void scan3_kernel(
    const int* __restrict__ A, const int* __restrict__ bpre, int* __restrict__ offs)
{
    int t = threadIdx.x;
    long long base = (long long)blockIdx.x * kChunk;
    int c[8]; int s = 0;
    #pragma unroll
    for (int j = 0; j < 8; ++j) {
        long long i = base + t * 8 + j;
        c[j] = (i < kN) ? A[i] : 0;
        s += c[j];
    }
    __shared__ int lds[256];
    lds[t] = s; __syncthreads();
    for (int st = 1; st < 256; st <<= 1) {
        int add = (t >= st) ? lds[t - st] : 0;
        __syncthreads();
        lds[t] += add;
        __syncthreads();
    }
    int excl = lds[t] - s + bpre[blockIdx.x];
    #pragma unroll
    for (int j = 0; j < 8; ++j) {
        long long i = base + t * 8 + j;
        if (i < kN) { offs[i] = excl; excl += c[j]; }
    }
}

__global__ __launch_bounds__(256) void scatter_kernel(
    const int* __restrict__ cidx, const int* __restrict__ offs,
    int* __restrict__ cur, int* __restrict__ sorted)
{
    int p = blockIdx.x * 256 + threadIdx.x;
    if (p < kNPair) {
        int r = cidx[p];
        int pos = offs[r] + atomicAdd(&cur[r], 1);
        sorted[pos] = p;   // bucket order nondeterministic; e values are not
    }
}

// ---------- fused v2: stream concat(S=[mem1|mem2]) once ----------
// Per wave-load j: 64 lanes x float4 = 1KB = rows 2j,2j+1 of one bank.
// Aligned shifted float4 store (out[1+g] = S[g]) built from shfl_up + carry.
// Dots against cache-resident teacher (bank1 -> e2) / student (bank2 -> e1)
// with a 5-level 32-lane butterfly; next load prefetched before the pair loop.
__global__ __launch_bounds__(256) void fused2_kernel(
    const float* __restrict__ mem1, const float* __restrict__ mem2,
    const float* __restrict__ teacher, const float* __restrict__ student,
    const int* __restrict__ offs, const int* __restrict__ sorted,
    float* __restrict__ out, float* __restrict__ e2, float* __restrict__ e1)
{
    const int lane = threadIdx.x & 63;
    const long long w = (long long)((blockIdx.x * 256 + threadIdx.x) >> 6);
    long long j0 = w * kIters;
    if (j0 >= kWL) return;
    long long jend = j0 + kIters; if (jend > kWL) jend = kWL;

    const float4* m1v = reinterpret_cast<const float4*>(mem1);
    const float4* m2v = reinterpret_cast<const float4*>(mem2);
    float4* ov = reinterpret_cast<float4*>(out);

    // initial carry = S[256*j0 - 1]
    float carry = 0.f;
    if (j0 > 0) {
        long long g = 256 * j0 - 1;
        carry = (g < kM) ? mem1[g] : mem2[g - kM];
    }

    float4 cur = (j0 < kWLB) ? m1v[j0 * 64 + lane] : m2v[(j0 - kWLB) * 64 + lane];

    for (long long j = j0; j < jend; ++j) {
        // prefetch next wave-load
        float4 nxt = make_float4(0.f, 0.f, 0.f, 0.f);
        long long jn = j + 1;
        if (jn < jend)
            nxt = (jn < kWLB) ? m1v[jn * 64 + lane] : m2v[(jn - kWLB) * 64 + lane];

        // shifted aligned store
        float pw = __shfl_up(cur.w, 1);
        if (lane == 0) pw = carry;
        carry = __shfl(cur.w, 63);
        long long k = j * 64 + lane;
        if (k != 0) {
            ov[k] = make_float4(pw, cur.x, cur.y, cur.z);
        } else {
            out[1] = cur.x; out[2] = cur.y; out[3] = cur.z;
        }

        // dots for the two rows in this wave-load
        bool b1 = (j < kWLB);
        long long jb = b1 ? j : j - kWLB;
        int r0 = (int)(2 * jb);
        int o0 = offs[r0], o1 = offs[r0 + 1], o2 = offs[r0 + 2];
        int cnt0 = o1 - o0, cnt1 = o2 - o1;
        int mc = cnt0 > cnt1 ? cnt0 : cnt1;
        if (mc > 0) {
            int h = lane >> 5;
            int myoff = h ? o1 : o0;
            int mycnt = h ? cnt1 : cnt0;
            const float* emb = b1 ? teacher : student;
            float* ep = b1 ? e2 : e1;
            for (int i = 0; i < mc; ++i) {
                bool act = (i < mycnt);
                int p = act ? sorted[myoff + i] : 0;
                unsigned bb = (unsigned)p / (unsigned)kKC;
                const float4 tv =
                    reinterpret_cast<const float4*>(emb + (long long)bb * kD)[lane & 31];
                float d = cur.x * tv.x + cur.y * tv.y + cur.z * tv.z + cur.w * tv.w;
                d += __shfl_xor(d, 16);
                d += __shfl_xor(d, 8);
                d += __shfl_xor(d, 4);
                d += __shfl_xor(d, 2);
                d += __shfl_xor(d, 1);
                if (((lane & 31) == 0) && act) ep[p] = __expf(d * kTInv);
            }
        }
        cur = nxt;
    }
    if (w == 0 && lane == 0) out[kTot] = mem2[kM - 1];   // final tail element
}

// ---------- fallback path (R2): separate gather + copy ----------

__global__ __launch_bounds__(256) void dots_kernel(
    const float* __restrict__ mem1, const float* __restrict__ mem2,
    const float* __restrict__ teacher, const float* __restrict__ student,
    const int* __restrict__ cidx,
    float* __restrict__ e2, float* __restrict__ e1)
{
    int gtid = blockIdx.x * 256 + threadIdx.x;
    int wave = gtid >> 6;
    int lane = threadIdx.x & 63;
    if (wave >= kNPair) return;
    int b = wave / kKC;
    long long row = (long long)cidx[wave] * kD;
    const float2 m1 = *reinterpret_cast<const float2*>(mem1 + row + lane * 2);
    const float2 m2 = *reinterpret_cast<const float2*>(mem2 + row + lane * 2);
    const float2 tv = *reinterpret_cast<const float2*>(teacher + b * kD + lane * 2);
    const float2 sv = *reinterpret_cast<const float2*>(student + b * kD + lane * 2);
    float d1 = m1.x * tv.x + m1.y * tv.y;
    float d2 = m2.x * sv.x + m2.y * sv.y;
    #pragma unroll
    for (int off = 32; off > 0; off >>= 1) {
        d1 += __shfl_xor(d1, off);
        d2 += __shfl_xor(d2, off);
    }
    if (lane == 0) {
        e2[wave] = __expf(d1 * kTInv);
        e1[wave] = __expf(d2 * kTInv);
    }
}

__global__ __launch_bounds__(256) void copy_kernel(
    const float* __restrict__ mem1, const float* __restrict__ mem2,
    float* __restrict__ out)
{
    const long long NV4 = (kTot + 1) / 4;
    const long long KS  = kM / 4;
    const float4* m1v = reinterpret_cast<const float4*>(mem1);
    const float4* m2v = reinterpret_cast<const float4*>(mem2);
    float4* ov = reinterpret_cast<float4*>(out);
    long long stride = (long long)gridDim.x * 256;
    for (long long k = (long long)blockIdx.x * 256 + threadIdx.x; k < NV4; k += stride) {
        if (k == 0) {
            out[1] = mem1[0]; out[2] = mem1[1]; out[3] = mem1[2];
            out[kTot] = mem2[kM - 1];
            continue;
        }
        float4 r;
        if (k < KS) {
            float4 a = m1v[k - 1];
            float4 b = m1v[k];
            r = make_float4(a.w, b.x, b.y, b.z);
        } else if (k == KS) {
            r = make_float4(mem1[kM - 1], mem2[0], mem2[1], mem2[2]);
        } else {
            float4 a = m2v[k - KS - 1];
            float4 b = m2v[k - KS];
            r = make_float4(a.w, b.x, b.y, b.z);
        }
        ov[k] = r;
    }
}

// ---------- loss chain ----------

__global__ __launch_bounds__(256) void sums_kernel(
    const float* __restrict__ e2, const float* __restrict__ e1,
    float* __restrict__ p2, float* __restrict__ p1)
{
    __shared__ float s2[256], s1[256];
    float a2 = 0.f, a1 = 0.f;
    for (int i = blockIdx.x * 256 + threadIdx.x; i < kNPair; i += 256 * kRB) {
        a2 += e2[i];
        a1 += e1[i];
    }
    s2[threadIdx.x] = a2; s1[threadIdx.x] = a1;
    __syncthreads();
    for (int st = 128; st > 0; st >>= 1) {
        if ((int)threadIdx.x < st) {
            s2[threadIdx.x] += s2[threadIdx.x + st];
            s1[threadIdx.x] += s1[threadIdx.x + st];
        }
        __syncthreads();
    }
    if (threadIdx.x == 0) { p2[blockIdx.x] = s2[0]; p1[blockIdx.x] = s1[0]; }
}

__global__ __launch_bounds__(256) void z_kernel(
    const float* __restrict__ p2, const float* __restrict__ p1, float* __restrict__ z)
{
    __shared__ float s2[256], s1[256];
    s2[threadIdx.x] = p2[threadIdx.x];
    s1[threadIdx.x] = p1[threadIdx.x];
    __syncthreads();
    for (int st = 128; st > 0; st >>= 1) {
        if ((int)threadIdx.x < st) {
            s2[threadIdx.x] += s2[threadIdx.x + st];
            s1[threadIdx.x] += s1[threadIdx.x + st];
        }
        __syncthreads();
    }
    if (threadIdx.x == 0) {
        const float scale = (float)kN / (float)kNPair;
        z[0] = s2[0] * scale;
        z[1] = s1[0] * scale;
    }
}

__global__ __launch_bounds__(256) void lossp_kernel(
    const float* __restrict__ e2, const float* __restrict__ e1,
    const float* __restrict__ z, float* __restrict__ lp)
{
    const float mpn = 2048.0f / 500000.0f;
    const float noise = mpn + 1e-7f;
    const float iz2 = 1.0f / z[0];
    const float iz1 = 1.0f / z[1];
    float acc = 0.f;
    for (int i = blockIdx.x * 256 + threadIdx.x; i < kNPair; i += 256 * kRB) {
        int k = i % kKC;
        float x2 = e2[i] * iz2;
        float x1 = e1[i] * iz1;
        if (k == 0) {
            acc += __logf(x2 / (x2 + noise)) + __logf(x1 / (x1 + noise));
        } else {
            acc += __logf(mpn / (x2 + noise)) + __logf(mpn / (x1 + noise));
        }
    }
    __shared__ float s[256];
    s[threadIdx.x] = acc;
    __syncthreads();
    for (int st = 128; st > 0; st >>= 1) {
        if ((int)threadIdx.x < st) s[threadIdx.x] += s[threadIdx.x + st];
        __syncthreads();
    }
    if (threadIdx.x == 0) lp[blockIdx.x] = s[0];
}

__global__ __launch_bounds__(256) void final_kernel(
    const float* __restrict__ lp, float* __restrict__ out)
{
    __shared__ float s[256];
    s[threadIdx.x] = lp[threadIdx.x];
    __syncthreads();
    for (int st = 128; st > 0; st >>= 1) {
        if ((int)threadIdx.x < st) s[threadIdx.x] += s[threadIdx.x + st];
        __syncthreads();
    }
    if (threadIdx.x == 0) out[0] = -s[0] / (float)kB;
}

// ---------- momentum update of the 256 pos rows ----------

__global__ __launch_bounds__(64) void update_kernel(
    const float* __restrict__ mem1, const float* __restrict__ mem2,
    const float* __restrict__ student, const float* __restrict__ teacher,
    const int* __restrict__ pos_idx,
    float* __restrict__ out1, float* __restrict__ out2)
{
    int b = blockIdx.x;
    int lane = threadIdx.x;
    int p = pos_idx[b];
    for (int b2 = b + 1; b2 < kB; ++b2)
        if (pos_idx[b2] == p) return;   // a later write wins
    long long row = (long long)p * kD;
    float2 m1 = *reinterpret_cast<const float2*>(mem1 + row + lane * 2);
    float2 m2 = *reinterpret_cast<const float2*>(mem2 + row + lane * 2);
    float2 sv = *reinterpret_cast<const float2*>(student + b * kD + lane * 2);
    float2 tv = *reinterpret_cast<const float2*>(teacher + b * kD + lane * 2);
    float2 l1 = make_float2(m1.x * kMom + sv.x * (1.f - kMom),
                            m1.y * kMom + sv.y * (1.f - kMom));
    float2 l2 = make_float2(m2.x * kMom + tv.x * (1.f - kMom),
                            m2.y * kMom + tv.y * (1.f - kMom));
    float n1 = l1.x * l1.x + l1.y * l1.y;
    float n2 = l2.x * l2.x + l2.y * l2.y;
    #pragma unroll
    for (int off = 32; off > 0; off >>= 1) {
        n1 += __shfl_xor(n1, off);
        n2 += __shfl_xor(n2, off);
    }
    float i1 = 1.0f / sqrtf(n1);
    float i2 = 1.0f / sqrtf(n2);
    out1[row + lane * 2]     = l1.x * i1;
    out1[row + lane * 2 + 1] = l1.y * i1;
    out2[row + lane * 2]     = l2.x * i2;
    out2[row + lane * 2 + 1] = l2.y * i2;
}

extern "C" void kernel_launch(void* const* d_in, const int* in_sizes, int n_in,
                              void* d_out, int out_size, void* d_ws, size_t ws_size,
                              hipStream_t stream) {
    const float* student = (const float*)d_in[0];
    const float* teacher = (const float*)d_in[1];
    const float* mem1    = (const float*)d_in[2];
    const float* mem2    = (const float*)d_in[3];
    const int*   pos_idx = (const int*)d_in[4];
    const int*   cidx    = (const int*)d_in[5];

    float* out  = (float*)d_out;
    float* out1 = out + 1;
    float* out2 = out + 1 + kM;

    // ws layout
    float* ws = (float*)d_ws;
    float* e2 = ws;                         // kNPair
    float* e1 = e2 + kNPair;                // kNPair
    float* p2 = e1 + kNPair;                // kRB
    float* p1 = p2 + kRB;                   // kRB
    float* zz = p1 + kRB;                   // 2
    float* lp = zz + 2;                     // kRB
    int*   A      = (int*)(lp + kRB);       // kN   (counts)
    int*   cur    = A + kN;                 // kN   (scatter cursor)
    int*   offs   = cur + kN;               // kN + 1
    int*   bsum   = offs + kN + 1;          // kNB1
    int*   bpre   = bsum + kNB1;            // kNB1
    int*   sorted = bpre + kNB1;            // kNPair
    size_t need = (size_t)((char*)(sorted + kNPair) - (char*)d_ws);

    if (ws_size >= need) {
        // CSR setup
        zero2_kernel<<<(kN + 255) / 256, 256, 0, stream>>>(A, cur);
        hist_kernel<<<(kNPair + 255) / 256, 256, 0, stream>>>(cidx, A);
        scan1_kernel<<<kNB1, 256, 0, stream>>>(A, bsum);
        scan2_kernel<<<1, 256, 0, stream>>>(bsum, bpre, offs);
        scan3_kernel<<<kNB1, 256, 0, stream>>>(A, bpre, offs);
        scatter_kernel<<<(kNPair + 255) / 256, 256, 0, stream>>>(cidx, offs, cur, sorted);
        // fused streaming copy + dots (8192 waves x 62 wave-loads)
        fused2_kernel<<<2048, 256, 0, stream>>>(mem1, mem2, teacher, student,
                                                offs, sorted, out, e2, e1);
    } else {
        // fallback: R2 path
        int nblocks = (kNPair + 3) / 4;
        dots_kernel<<<nblocks, 256, 0, stream>>>(mem1, mem2, teacher, student, cidx, e2, e1);
        copy_kernel<<<2048, 256, 0, stream>>>(mem1, mem2, out);
    }

    sums_kernel<<<kRB, 256, 0, stream>>>(e2, e1, p2, p1);
    z_kernel<<<1, 256, 0, stream>>>(p2, p1, zz);
    lossp_kernel<<<kRB, 256, 0, stream>>>(e2, e1, zz, lp);
    final_kernel<<<1, 256, 0, stream>>>(lp, out);
    update_kernel<<<kB, 64, 0, stream>>>(mem1, mem2, student, teacher, pos_idx, out1, out2);
}

// Round 5
// 329.665 us; speedup vs baseline: 1.2052x; 1.1311x over previous
//
#include <hip/hip_runtime.h>
#include <math.h>

namespace {
constexpr int kB = 256;
constexpr int kD = 128;
constexpr int kN = 500000;
constexpr int kKC = 2049;             // K + 1
constexpr int kNPair = kB * kKC;      // 524544
constexpr float kTInv = 1.0f / 0.07f;
constexpr float kMom = 0.5f;
constexpr int kRB = 256;              // reduction grid size
constexpr long long kM = (long long)kN * kD;    // 64,000,000 floats per bank
constexpr long long kTot = 2 * kM;
constexpr int kChunk = 2048;                    // elems per scan block
constexpr int kNB1 = (kN + kChunk - 1) / kChunk; // 245
constexpr int kRows = 64;                        // rows per tile
constexpr int kTPB = (kN + kRows - 1) / kRows;   // 7813 tiles per bank
constexpr int kTiles = 2 * kTPB;                 // 15626
constexpr int kLdsStride = 132;                  // 528 B row pitch (16B-aligned, spreads banks)
constexpr int kTilesPerBlock = 8;
constexpr int kGrid3 = (kTiles + kTilesPerBlock - 1) / kTilesPerBlock; // 1954
}

// ---------- CSR setup: bucket pairs by row index ----------

__global__ __launch_bounds__(256) void zero2_kernel(int* __restrict__ A, int* __restrict__ cur)
{
    int i = blockIdx.x * 256 + threadIdx.x;
    if (i < kN) { A[i] = 0; cur[i] = 0; }
}

__global__ __launch_bounds__(256) void hist_kernel(const int* __restrict__ cidx, int* __restrict__ A)
{
    int i = blockIdx.x * 256 + threadIdx.x;
    if (i < kNPair) atomicAdd(&A[cidx[i]], 1);
}

__global__ __launch_bounds__(256) void scan1_kernel(const int* __restrict__ A, int* __restrict__ bsum)
{
    long long base = (long long)blockIdx.x * kChunk;
    int t = threadIdx.x;
    int s = 0;
    #pragma unroll
    for (int j = 0; j < 8; ++j) {
        long long i = base + t * 8 + j;
        if (i < kN) s += A[i];
    }
    __shared__ int lds[256];
    lds[t] = s; __syncthreads();
    for (int st = 128; st > 0; st >>= 1) {
        if (t < st) lds[t] += lds[t + st];
        __syncthreads();
    }
    if (t == 0) bsum[blockIdx.x] = lds[0];
}

__global__ __launch_bounds__(256) void scan2_kernel(
    const int* __restrict__ bsum, int* __restrict__ bpre, int* __restrict__ offs)
{
    int t = threadIdx.x;
    int v = (t < kNB1) ? bsum[t] : 0;
    __shared__ int lds[256];
    lds[t] = v; __syncthreads();
    for (int st = 1; st < 256; st <<= 1) {
        int add = (t >= st) ? lds[t - st] : 0;
        __syncthreads();
        lds[t] += add;
        __syncthreads();
    }
    if (t < kNB1) bpre[t] = lds[t] - v;       // exclusive
    if (t == kNB1 - 1) offs[kN] = lds[t];     // total = kNPair
}

__global__ __launch_bounds__(256) void scan3_kernel(
    const int* __restrict__ A, const int* __restrict__ bpre, int* __restrict__ offs)
{
    int t = threadIdx.x;
    long long base = (long long)blockIdx.x * kChunk;
    int c[8]; int s = 0;
    #pragma unroll
    for (int j = 0; j < 8; ++j) {
        long long i = base + t * 8 + j;
        c[j] = (i < kN) ? A[i] : 0;
        s += c[j];
    }
    __shared__ int lds[256];
    lds[t] = s; __syncthreads();
    for (int st = 1; st < 256; st <<= 1) {
        int add = (t >= st) ? lds[t - st] : 0;
        __syncthreads();
        lds[t] += add;
        __syncthreads();
    }
    int excl = lds[t] - s + bpre[blockIdx.x];
    #pragma unroll
    for (int j = 0; j < 8; ++j) {
        long long i = base + t * 8 + j;
        if (i < kN) { offs[i] = excl; excl += c[j]; }
    }
}

__global__ __launch_bounds__(256) void scatter_kernel(
    const int* __restrict__ cidx, const int* __restrict__ offs,
    int* __restrict__ cur, int* __restrict__ sorted)
{
    int p = blockIdx.x * 256 + threadIdx.x;
    if (p < kNPair) {
        int r = cidx[p];
        int pos = offs[r] + atomicAdd(&cur[r], 1);
        sorted[pos] = p;   // bucket order nondeterministic; e values are not
    }
}

// ---------- fused v3: tile-stage in LDS, pair-per-lane dots (no shuffles) ----------
// Per tile (64 rows of one bank): Phase A streams the 32KB tile HBM->reg,
// writes shifted aligned float4 output (carry trick) and stages rows in LDS
// (132-float pitch: 16B-aligned, near-optimal bank spread). Phase B: one pair
// per LANE reads its full row from LDS (32x ds_read_b128, independent) and
// dots against L2-resident teacher/student; no cross-lane reduction at all.
__global__ __launch_bounds__(256) void fused3_kernel(
    const float* __restrict__ mem1, const float* __restrict__ mem2,
    const float* __restrict__ teacher, const float* __restrict__ student,
    const int* __restrict__ offs, const int* __restrict__ sorted,
    const int* __restrict__ cidx,
    float* __restrict__ out, float* __restrict__ e2, float* __restrict__ e1)
{
    __shared__ float tile[kRows * kLdsStride];
    const int tid = threadIdx.x;
    const int lane = tid & 63;
    const int w = tid >> 6;
    float4* ov = reinterpret_cast<float4*>(out);

    if (blockIdx.x == 0 && tid == 0) out[kTot] = mem2[kM - 1];  // final tail

    int T0 = blockIdx.x * kTilesPerBlock;
    int T1 = T0 + kTilesPerBlock; if (T1 > kTiles) T1 = kTiles;
    for (int T = T0; T < T1; ++T) {
        int bk = (T >= kTPB) ? 1 : 0;
        int tt = T - bk * kTPB;
        int r0 = tt * kRows;
        int R  = kN - r0; if (R > kRows) R = kRows;

        if (w * 16 < R) {
            const float4* bank4 = reinterpret_cast<const float4*>(bk ? mem2 : mem1);
            long long chunk = (long long)r0 * kD + w * 2048;   // bank-local float idx
            long long cb4   = chunk >> 2;
            long long base4 = (((long long)bk * kM) + chunk) >> 2;
            float4 v[8];
            #pragma unroll
            for (int i = 0; i < 8; ++i) v[i] = bank4[cb4 + i * 64 + lane];
            float carry = 0.f;
            long long gg = (long long)bk * kM + chunk - 1;
            if (gg >= 0) carry = (gg < kM) ? mem1[gg] : mem2[gg - kM];
            #pragma unroll
            for (int i = 0; i < 8; ++i) {
                float4 cur = v[i];
                int lr  = w * 16 + i * 2 + (lane >> 5);
                int col = (lane & 31) * 4;
                *reinterpret_cast<float4*>(&tile[lr * kLdsStride + col]) = cur;
                float pw = __shfl_up(cur.w, 1);
                if (lane == 0) pw = carry;
                carry = __shfl(cur.w, 63);
                long long k4 = base4 + i * 64 + lane;
                if (k4 != 0) {
                    ov[k4] = make_float4(pw, cur.x, cur.y, cur.z);
                } else {
                    out[1] = cur.x; out[2] = cur.y; out[3] = cur.z;
                }
            }
        }
        __syncthreads();

        int o0  = offs[r0];
        int cnt = offs[r0 + R] - o0;
        const float* emb = bk ? student : teacher;
        float* ep = bk ? e1 : e2;
        for (int t = tid; t < cnt; t += 256) {
            int p  = sorted[o0 + t];
            int lr = cidx[p] - r0;
            unsigned b = (unsigned)p / (unsigned)kKC;
            const float4* er = reinterpret_cast<const float4*>(emb + (long long)b * kD);
            const float* row = &tile[lr * kLdsStride];
            float ax = 0.f, ay = 0.f, az = 0.f, aw = 0.f;
            #pragma unroll 8
            for (int kk = 0; kk < 32; ++kk) {
                float4 rv = *reinterpret_cast<const float4*>(&row[kk * 4]);
                float4 ev = er[kk];
                ax += rv.x * ev.x; ay += rv.y * ev.y;
                az += rv.z * ev.z; aw += rv.w * ev.w;
            }
            ep[p] = __expf((ax + ay + az + aw) * kTInv);
        }
        __syncthreads();
    }
}

// ---------- fallback path (R2): separate gather + copy ----------

__global__ __launch_bounds__(256) void dots_kernel(
    const float* __restrict__ mem1, const float* __restrict__ mem2,
    const float* __restrict__ teacher, const float* __restrict__ student,
    const int* __restrict__ cidx,
    float* __restrict__ e2, float* __restrict__ e1)
{
    int gtid = blockIdx.x * 256 + threadIdx.x;
    int wave = gtid >> 6;
    int lane = threadIdx.x & 63;
    if (wave >= kNPair) return;
    int b = wave / kKC;
    long long row = (long long)cidx[wave] * kD;
    const float2 m1 = *reinterpret_cast<const float2*>(mem1 + row + lane * 2);
    const float2 m2 = *reinterpret_cast<const float2*>(mem2 + row + lane * 2);
    const float2 tv = *reinterpret_cast<const float2*>(teacher + b * kD + lane * 2);
    const float2 sv = *reinterpret_cast<const float2*>(student + b * kD + lane * 2);
    float d1 = m1.x * tv.x + m1.y * tv.y;
    float d2 = m2.x * sv.x + m2.y * sv.y;
    #pragma unroll
    for (int off = 32; off > 0; off >>= 1) {
        d1 += __shfl_xor(d1, off);
        d2 += __shfl_xor(d2, off);
    }
    if (lane == 0) {
        e2[wave] = __expf(d1 * kTInv);
        e1[wave] = __expf(d2 * kTInv);
    }
}

__global__ __launch_bounds__(256) void copy_kernel(
    const float* __restrict__ mem1, const float* __restrict__ mem2,
    float* __restrict__ out)
{
    const long long NV4 = (kTot + 1) / 4;
    const long long KS  = kM / 4;
    const float4* m1v = reinterpret_cast<const float4*>(mem1);
    const float4* m2v = reinterpret_cast<const float4*>(mem2);
    float4* ov = reinterpret_cast<float4*>(out);
    long long stride = (long long)gridDim.x * 256;
    for (long long k = (long long)blockIdx.x * 256 + threadIdx.x; k < NV4; k += stride) {
        if (k == 0) {
            out[1] = mem1[0]; out[2] = mem1[1]; out[3] = mem1[2];
            out[kTot] = mem2[kM - 1];
            continue;
        }
        float4 r;
        if (k < KS) {
            float4 a = m1v[k - 1];
            float4 b = m1v[k];
            r = make_float4(a.w, b.x, b.y, b.z);
        } else if (k == KS) {
            r = make_float4(mem1[kM - 1], mem2[0], mem2[1], mem2[2]);
        } else {
            float4 a = m2v[k - KS - 1];
            float4 b = m2v[k - KS];
            r = make_float4(a.w, b.x, b.y, b.z);
        }
        ov[k] = r;
    }
}

// ---------- loss chain ----------

__global__ __launch_bounds__(256) void sums_kernel(
    const float* __restrict__ e2, const float* __restrict__ e1,
    float* __restrict__ p2, float* __restrict__ p1)
{
    __shared__ float s2[256], s1[256];
    float a2 = 0.f, a1 = 0.f;
    for (int i = blockIdx.x * 256 + threadIdx.x; i < kNPair; i += 256 * kRB) {
        a2 += e2[i];
        a1 += e1[i];
    }
    s2[threadIdx.x] = a2; s1[threadIdx.x] = a1;
    __syncthreads();
    for (int st = 128; st > 0; st >>= 1) {
        if ((int)threadIdx.x < st) {
            s2[threadIdx.x] += s2[threadIdx.x + st];
            s1[threadIdx.x] += s1[threadIdx.x + st];
        }
        __syncthreads();
    }
    if (threadIdx.x == 0) { p2[blockIdx.x] = s2[0]; p1[blockIdx.x] = s1[0]; }
}

__global__ __launch_bounds__(256) void z_kernel(
    const float* __restrict__ p2, const float* __restrict__ p1, float* __restrict__ z)
{
    __shared__ float s2[256], s1[256];
    s2[threadIdx.x] = p2[threadIdx.x];
    s1[threadIdx.x] = p1[threadIdx.x];
    __syncthreads();
    for (int st = 128; st > 0; st >>= 1) {
        if ((int)threadIdx.x < st) {
            s2[threadIdx.x] += s2[threadIdx.x + st];
            s1[threadIdx.x] += s1[threadIdx.x + st];
        }
        __syncthreads();
    }
    if (threadIdx.x == 0) {
        const float scale = (float)kN / (float)kNPair;
        z[0] = s2[0] * scale;
        z[1] = s1[0] * scale;
    }
}

__global__ __launch_bounds__(256) void lossp_kernel(
    const float* __restrict__ e2, const float* __restrict__ e1,
    const float* __restrict__ z, float* __restrict__ lp)
{
    const float mpn = 2048.0f / 500000.0f;
    const float noise = mpn + 1e-7f;
    const float iz2 = 1.0f / z[0];
    const float iz1 = 1.0f / z[1];
    float acc = 0.f;
    for (int i = blockIdx.x * 256 + threadIdx.x; i < kNPair; i += 256 * kRB) {
        int k = i % kKC;
        float x2 = e2[i] * iz2;
        float x1 = e1[i] * iz1;
        if (k == 0) {
            acc += __logf(x2 / (x2 + noise)) + __logf(x1 / (x1 + noise));
        } else {
            acc += __logf(mpn / (x2 + noise)) + __logf(mpn / (x1 + noise));
        }
    }
    __shared__ float s[256];
    s[threadIdx.x] = acc;
    __syncthreads();
    for (int st = 128; st > 0; st >>= 1) {
        if ((int)threadIdx.x < st) s[threadIdx.x] += s[threadIdx.x + st];
        __syncthreads();
    }
    if (threadIdx.x == 0) lp[blockIdx.x] = s[0];
}

__global__ __launch_bounds__(256) void final_kernel(
    const float* __restrict__ lp, float* __restrict__ out)
{
    __shared__ float s[256];
    s[threadIdx.x] = lp[threadIdx.x];
    __syncthreads();
    for (int st = 128; st > 0; st >>= 1) {
        if ((int)threadIdx.x < st) s[threadIdx.x] += s[threadIdx.x + st];
        __syncthreads();
    }
    if (threadIdx.x == 0) out[0] = -s[0] / (float)kB;
}

// ---------- momentum update of the 256 pos rows ----------

__global__ __launch_bounds__(64) void update_kernel(
    const float* __restrict__ mem1, const float* __restrict__ mem2,
    const float* __restrict__ student, const float* __restrict__ teacher,
    const int* __restrict__ pos_idx,
    float* __restrict__ out1, float* __restrict__ out2)
{
    int b = blockIdx.x;
    int lane = threadIdx.x;
    int p = pos_idx[b];
    for (int b2 = b + 1; b2 < kB; ++b2)
        if (pos_idx[b2] == p) return;   // a later write wins
    long long row = (long long)p * kD;
    float2 m1 = *reinterpret_cast<const float2*>(mem1 + row + lane * 2);
    float2 m2 = *reinterpret_cast<const float2*>(mem2 + row + lane * 2);
    float2 sv = *reinterpret_cast<const float2*>(student + b * kD + lane * 2);
    float2 tv = *reinterpret_cast<const float2*>(teacher + b * kD + lane * 2);
    float2 l1 = make_float2(m1.x * kMom + sv.x * (1.f - kMom),
                            m1.y * kMom + sv.y * (1.f - kMom));
    float2 l2 = make_float2(m2.x * kMom + tv.x * (1.f - kMom),
                            m2.y * kMom + tv.y * (1.f - kMom));
    float n1 = l1.x * l1.x + l1.y * l1.y;
    float n2 = l2.x * l2.x + l2.y * l2.y;
    #pragma unroll
    for (int off = 32; off > 0; off >>= 1) {
        n1 += __shfl_xor(n1, off);
        n2 += __shfl_xor(n2, off);
    }
    float i1 = 1.0f / sqrtf(n1);
    float i2 = 1.0f / sqrtf(n2);
    out1[row + lane * 2]     = l1.x * i1;
    out1[row + lane * 2 + 1] = l1.y * i1;
    out2[row + lane * 2]     = l2.x * i2;
    out2[row + lane * 2 + 1] = l2.y * i2;
}

extern "C" void kernel_launch(void* const* d_in, const int* in_sizes, int n_in,
                              void* d_out, int out_size, void* d_ws, size_t ws_size,
                              hipStream_t stream) {
    const float* student = (const float*)d_in[0];
    const float* teacher = (const float*)d_in[1];
    const float* mem1    = (const float*)d_in[2];
    const float* mem2    = (const float*)d_in[3];
    const int*   pos_idx = (const int*)d_in[4];
    const int*   cidx    = (const int*)d_in[5];

    float* out  = (float*)d_out;
    float* out1 = out + 1;
    float* out2 = out + 1 + kM;

    // ws layout
    float* ws = (float*)d_ws;
    float* e2 = ws;                         // kNPair
    float* e1 = e2 + kNPair;                // kNPair
    float* p2 = e1 + kNPair;                // kRB
    float* p1 = p2 + kRB;                   // kRB
    float* zz = p1 + kRB;                   // 2
    float* lp = zz + 2;                     // kRB
    int*   A      = (int*)(lp + kRB);       // kN   (counts)
    int*   cur    = A + kN;                 // kN   (scatter cursor)
    int*   offs   = cur + kN;               // kN + 1
    int*   bsum   = offs + kN + 1;          // kNB1
    int*   bpre   = bsum + kNB1;            // kNB1
    int*   sorted = bpre + kNB1;            // kNPair
    size_t need = (size_t)((char*)(sorted + kNPair) - (char*)d_ws);

    if (ws_size >= need) {
        // CSR setup
        zero2_kernel<<<(kN + 255) / 256, 256, 0, stream>>>(A, cur);
        hist_kernel<<<(kNPair + 255) / 256, 256, 0, stream>>>(cidx, A);
        scan1_kernel<<<kNB1, 256, 0, stream>>>(A, bsum);
        scan2_kernel<<<1, 256, 0, stream>>>(bsum, bpre, offs);
        scan3_kernel<<<kNB1, 256, 0, stream>>>(A, bpre, offs);
        scatter_kernel<<<(kNPair + 255) / 256, 256, 0, stream>>>(cidx, offs, cur, sorted);
        // fused tiled copy + dots
        fused3_kernel<<<kGrid3, 256, 0, stream>>>(mem1, mem2, teacher, student,
                                                  offs, sorted, cidx, out, e2, e1);
    } else {
        // fallback: R2 path
        int nblocks = (kNPair + 3) / 4;
        dots_kernel<<<nblocks, 256, 0, stream>>>(mem1, mem2, teacher, student, cidx, e2, e1);
        copy_kernel<<<2048, 256, 0, stream>>>(mem1, mem2, out);
    }

    sums_kernel<<<kRB, 256, 0, stream>>>(e2, e1, p2, p1);
    z_kernel<<<1, 256, 0, stream>>>(p2, p1, zz);
    lossp_kernel<<<kRB, 256, 0, stream>>>(e2, e1, zz, lp);
    final_kernel<<<1, 256, 0, stream>>>(lp, out);
    update_kernel<<<kB, 64, 0, stream>>>(mem1, mem2, student, teacher, pos_idx, out1, out2);
}